// Round 1
// baseline (214.124 us; speedup 1.0000x reference)
//
#include <hip/hip_runtime.h>
#include <math.h>

#define SS 4096
#define EE 1024
#define HH 16
#define DD 64

// ---------------------------------------------------------------------------
// ws layout (floats):
//   [0..63]    : meta ints (s0, L) in first 2 ints
//   [64..1087] : sumx[E]   (column sum of x, atomically accumulated)
//   [1088..2111]: bg[E]    (V_all - V_seg background vector)
//   [2112..3135]: mwv[E]   (mean wv over segment)
//   byte 16384 onward: qb/kb/vb, each caprows*E floats
//     qb is overwritten in-place with wv by the attention kernel.
// ---------------------------------------------------------------------------

__global__ void seg_kernel(const int* seg, const int* posp, int* meta, int caprows) {
    __shared__ int smin, smax;
    if (threadIdx.x == 0) { smin = SS; smax = -1; }
    __syncthreads();
    int sid = seg[posp[0]];
    int lmin = SS, lmax = -1;
    for (int i = threadIdx.x; i < SS; i += blockDim.x) {
        if (seg[i] == sid) { lmin = min(lmin, i); lmax = max(lmax, i); }
    }
    atomicMin(&smin, lmin);
    atomicMax(&smax, lmax);
    __syncthreads();
    if (threadIdx.x == 0) {
        int s0 = smin;
        int L  = smax - smin + 1;
        if (L > caprows - 1) L = caprows - 1;  // capacity safety clamp
        meta[0] = s0;
        meta[1] = L;
    }
}

// column sum of x -> sumx[E]; grid (4, 64), block 256
__global__ void sumx_kernel(const float* __restrict__ x, float* __restrict__ sumx) {
    int e  = blockIdx.x * 256 + threadIdx.x;
    int r0 = blockIdx.y * (SS / 64);
    float a = 0.f;
    for (int r = r0; r < r0 + SS / 64; ++r) a += x[(size_t)r * EE + e];
    atomicAdd(&sumx[e], a);
}

// q/k/v projections for segment rows + one extra "sumx" row (V_all for m==2).
// One wave per (matrix m, output col e, 32-row chunk). Persistent grid.
__global__ __launch_bounds__(64) void proj_kernel(
    const float* __restrict__ x,
    const float* __restrict__ Wq, const float* __restrict__ bq,
    const float* __restrict__ Wk, const float* __restrict__ bk,
    const float* __restrict__ Wv, const float* __restrict__ bv,
    const int* __restrict__ meta, const float* __restrict__ sumx,
    float* __restrict__ qb, float* __restrict__ kb, float* __restrict__ vb) {
    int s0 = meta[0], L = meta[1];
    int R    = L + 1;                 // +1 virtual row = sumx
    int nch  = (R + 31) / 32;
    int perm = EE * nch;
    int total = 3 * perm;
    int lane = threadIdx.x;
    for (int it = blockIdx.x; it < total; it += gridDim.x) {
        int m  = it / perm;
        int r  = it - m * perm;
        int e  = r % EE;
        int ch = r / EE;
        const float* W = (m == 0) ? Wq : ((m == 1) ? Wk : Wv);
        const float* b = (m == 0) ? bq : ((m == 1) ? bk : bv);
        float*       y = (m == 0) ? qb : ((m == 1) ? kb : vb);
        int sb = ch * 32;
        const float* rp[32];
#pragma unroll
        for (int i = 0; i < 32; ++i) {
            int sr = sb + i;
            rp[i] = (sr < L) ? (x + (size_t)(s0 + sr) * EE) : sumx;
        }
        float acc[32];
#pragma unroll
        for (int i = 0; i < 32; ++i) acc[i] = 0.f;
        const float* wrow = W + (size_t)e * EE;
        for (int j0 = 0; j0 < EE; j0 += 64) {
            float w = wrow[j0 + lane];
#pragma unroll
            for (int i = 0; i < 32; ++i) acc[i] += w * rp[i][j0 + lane];
        }
#pragma unroll
        for (int i = 0; i < 32; ++i) {
            float v = acc[i];
#pragma unroll
            for (int off = 32; off; off >>= 1) v += __shfl_xor(v, off);
            int sr = sb + i;
            if (lane == 0 && sr <= L) {
                float bias = b[e];
                y[(size_t)sr * EE + e] = v + ((sr == L) ? (float)SS * bias : bias);
            }
        }
    }
}

// bg[e] = V_all[e] - sum_{t in seg} v[t][e]   (V_all stored as vb row L)
__global__ void bg_kernel(const int* __restrict__ meta, const float* __restrict__ vb,
                          float* __restrict__ bg) {
    int L = meta[1];
    int e = blockIdx.x * blockDim.x + threadIdx.x;
    float a = 0.f;
    for (int t = 0; t < L; ++t) a += vb[(size_t)t * EE + e];
    bg[e] = vb[(size_t)L * EE + e] - a;
}

// attention for one (segment-row, head) per wave; writes wv over qb in place.
__global__ __launch_bounds__(64) void attn_kernel(
    const int* __restrict__ meta, float* __restrict__ qb,
    const float* __restrict__ kb, const float* __restrict__ vb,
    const float* __restrict__ bg) {
    int L = meta[1];
    int lane = threadIdx.x;
    int total = L * HH;
    for (int it = blockIdx.x; it < total; it += gridDim.x) {
        int h  = it % HH;
        int sl = it / HH;
        float qd = qb[(size_t)sl * EE + h * DD + lane];
        const float* kh = kb + h * DD;
        const float* vh = vb + h * DD;
        // pass 1: row max. Out-of-segment entries contribute score 0 (L<S).
        float mmax = (L < SS) ? 0.f : -3.4e38f;
        for (int t = 0; t < L; ++t) {
            float p = qd * kh[(size_t)t * EE + lane];
#pragma unroll
            for (int off = 32; off; off >>= 1) p += __shfl_xor(p, off);
            mmax = fmaxf(mmax, p);
        }
        // pass 2: Z and weighted v-sum
        float Z   = (L < SS) ? (float)(SS - L) * expf(-mmax) : 0.f;
        float acc = 0.f;
        for (int t = 0; t < L; ++t) {
            float p = qd * kh[(size_t)t * EE + lane];
#pragma unroll
            for (int off = 32; off; off >>= 1) p += __shfl_xor(p, off);
            float w = expf(p - mmax);
            Z   += w;
            acc += w * vh[(size_t)t * EE + lane];
        }
        float o = (acc + expf(-mmax) * bg[h * DD + lane]) / Z;
        qb[(size_t)sl * EE + h * DD + lane] = o;   // qb becomes wv
    }
}

// mean of wv rows over the segment
__global__ void mean_kernel(const int* __restrict__ meta, const float* __restrict__ wv,
                            float* __restrict__ mwv) {
    int L = meta[1];
    int e = blockIdx.x * blockDim.x + threadIdx.x;
    float a = 0.f;
    for (int s = 0; s < L; ++s) a += wv[(size_t)s * EE + e];
    mwv[e] = a / (float)L;
}

// out[e] = mwv . Wo[e,:] + bo[e]; one wave per output element
__global__ __launch_bounds__(256) void out_kernel(const float* __restrict__ mwv,
                                                  const float* __restrict__ Wo,
                                                  const float* __restrict__ bo,
                                                  float* __restrict__ out) {
    int gid  = blockIdx.x * blockDim.x + threadIdx.x;
    int e    = gid / 64;
    int lane = gid % 64;
    float a = 0.f;
    const float* wrow = Wo + (size_t)e * EE;
    for (int j0 = 0; j0 < EE; j0 += 64) a += mwv[j0 + lane] * wrow[j0 + lane];
#pragma unroll
    for (int off = 32; off; off >>= 1) a += __shfl_xor(a, off);
    if (lane == 0) out[e] = a + bo[e];
}

extern "C" void kernel_launch(void* const* d_in, const int* in_sizes, int n_in,
                              void* d_out, int out_size, void* d_ws, size_t ws_size,
                              hipStream_t stream) {
    const float* x   = (const float*)d_in[0];
    const float* Wq  = (const float*)d_in[1];
    const float* bq  = (const float*)d_in[2];
    const float* Wk  = (const float*)d_in[3];
    const float* bk  = (const float*)d_in[4];
    const float* Wv  = (const float*)d_in[5];
    const float* bv  = (const float*)d_in[6];
    const float* Wo  = (const float*)d_in[7];
    const float* bo  = (const float*)d_in[8];
    const int*   seg = (const int*)d_in[9];
    const int*   pos = (const int*)d_in[10];
    float*       out = (float*)d_out;

    int*   meta = (int*)d_ws;
    float* fws  = (float*)d_ws;
    float* sumx = fws + 64;
    float* bg   = fws + 64 + EE;
    float* mwv  = fws + 64 + 2 * EE;

    size_t avail  = (ws_size > 16384) ? (ws_size - 16384) : 0;
    int    caprows = (int)(avail / (3ull * EE * sizeof(float)));
    if (caprows > SS + 1) caprows = SS + 1;
    float* qb = (float*)((char*)d_ws + 16384);
    float* kb = qb + (size_t)caprows * EE;
    float* vb = kb + (size_t)caprows * EE;

    // zero the atomic accumulator region
    hipMemsetAsync(sumx, 0, EE * sizeof(float), stream);

    seg_kernel<<<1, 256, 0, stream>>>(seg, pos, meta, caprows);
    sumx_kernel<<<dim3(4, 64), 256, 0, stream>>>(x, sumx);
    proj_kernel<<<3072, 64, 0, stream>>>(x, Wq, bq, Wk, bk, Wv, bv, meta, sumx,
                                         qb, kb, vb);
    bg_kernel<<<4, 256, 0, stream>>>(meta, vb, bg);
    attn_kernel<<<1024, 64, 0, stream>>>(meta, qb, kb, vb, bg);
    mean_kernel<<<4, 256, 0, stream>>>(meta, qb, mwv);
    out_kernel<<<256, 256, 0, stream>>>(mwv, Wo, bo, out);
}

// Round 2
// 145.764 us; speedup vs baseline: 1.4690x; 1.4690x over previous
//
#include <hip/hip_runtime.h>
#include <math.h>

#define SS 4096
#define EE 1024
#define HH 16
#define DD 64
#define LP 512   // fixed leading-dim (max supported segment length) for kt

// ---------------------------------------------------------------------------
// ws layout:
//   ints[0..1]              : meta (s0, L)
//   floats 64..(64+E)       : sumx[E]
//   floats ..+E             : bg[E]
//   floats ..+E             : mwv[E]  (atomic-accumulated SUM of wv rows)
//   byte 16384 onward       : qb, kb, vb (caprows*E floats each), kt (E*LP)
//   qb is overwritten in-place with wv by the attention kernel.
// ---------------------------------------------------------------------------

// sumx (column sum of x) + segment-range scan fused. grid (4,64), block 256.
__global__ void prep_kernel(const float* __restrict__ x,
                            const int* __restrict__ seg, const int* __restrict__ posp,
                            float* __restrict__ sumx, int* __restrict__ meta,
                            int caprows) {
    int e  = blockIdx.x * 256 + threadIdx.x;
    int r0 = blockIdx.y * (SS / 64);
    float a = 0.f;
    for (int r = r0; r < r0 + SS / 64; ++r) a += x[(size_t)r * EE + e];
    atomicAdd(&sumx[e], a);

    if (blockIdx.x == 0 && blockIdx.y == 0) {
        __shared__ int smin, smax;
        if (threadIdx.x == 0) { smin = SS; smax = -1; }
        __syncthreads();
        int sid = seg[posp[0]];
        int lmin = SS, lmax = -1;
        for (int i = threadIdx.x; i < SS; i += 256) {
            if (seg[i] == sid) { lmin = min(lmin, i); lmax = max(lmax, i); }
        }
        atomicMin(&smin, lmin);
        atomicMax(&smax, lmax);
        __syncthreads();
        if (threadIdx.x == 0) {
            int L = smax - smin + 1;
            if (L > caprows - 64) L = caprows - 64;  // safety clamps
            if (L > LP) L = LP;
            meta[0] = smin;
            meta[1] = L;
        }
    }
}

// q/k/v projections for the L segment rows.
// Block = 256 thr (4 waves). Per item: stage 16 x-rows in LDS, each wave
// computes 4 output columns over all 16 rows. Persistent grid.
__global__ __launch_bounds__(256) void proj_kernel(
    const float* __restrict__ x,
    const float* __restrict__ Wq, const float* __restrict__ bq,
    const float* __restrict__ Wk, const float* __restrict__ bk,
    const float* __restrict__ Wv, const float* __restrict__ bv,
    const int* __restrict__ meta,
    float* __restrict__ qb, float* __restrict__ kb, float* __restrict__ vb) {
    __shared__ float xs[16][EE];
    int s0 = meta[0], L = meta[1];
    int nch   = (L + 15) >> 4;
    int perm  = nch * 64;           // 64 e-groups of 16
    int total = 3 * perm;
    int tid  = threadIdx.x;
    int wave = tid >> 6, lane = tid & 63;
    for (int it = blockIdx.x; it < total; it += gridDim.x) {
        int m   = it / perm;
        int rem = it - m * perm;
        int ch  = rem >> 6;         // ch-major so consecutive blocks share W rows
        int eg  = rem & 63;
        const float* W = (m == 0) ? Wq : ((m == 1) ? Wk : Wv);
        const float* b = (m == 0) ? bq : ((m == 1) ? bk : bv);
        float*       y = (m == 0) ? qb : ((m == 1) ? kb : vb);
        int rbase = ch << 4;
        __syncthreads();
        for (int idx = tid; idx < 16 * EE; idx += 256) {
            int r = idx >> 10, c = idx & 1023;
            int row = rbase + r;
            xs[r][c] = (row < L) ? x[(size_t)(s0 + row) * EE + c] : 0.f;
        }
        __syncthreads();
        int e0 = (eg << 4) + (wave << 2);
        float acc[4][16];
#pragma unroll
        for (int j = 0; j < 4; ++j)
#pragma unroll
            for (int i = 0; i < 16; ++i) acc[j][i] = 0.f;
        for (int j0 = 0; j0 < EE; j0 += 64) {
            float wv[4];
#pragma unroll
            for (int j = 0; j < 4; ++j) wv[j] = W[(size_t)(e0 + j) * EE + j0 + lane];
            float xr[16];
#pragma unroll
            for (int i = 0; i < 16; ++i) xr[i] = xs[i][j0 + lane];
#pragma unroll
            for (int j = 0; j < 4; ++j)
#pragma unroll
                for (int i = 0; i < 16; ++i) acc[j][i] += wv[j] * xr[i];
        }
#pragma unroll
        for (int j = 0; j < 4; ++j) {
#pragma unroll
            for (int i = 0; i < 16; ++i) {
                float v = acc[j][i];
#pragma unroll
                for (int off = 32; off; off >>= 1) v += __shfl_xor(v, off);
                int row = rbase + i;
                if (lane == 0 && row < L)
                    y[(size_t)row * EE + e0 + j] = v + b[e0 + j];
            }
        }
    }
}

// kt[e][t] = kb[t][e], LDS-tiled transpose. grid (8,16), block 256.
__global__ void kt_kernel(const int* __restrict__ meta, const float* __restrict__ kb,
                          float* __restrict__ kt) {
    __shared__ float tile[64][65];
    int L = meta[1];
    int t0 = blockIdx.x * 64;
    if (t0 >= L) return;
    int e0 = blockIdx.y * 64;
    int tid = threadIdx.x;
    for (int idx = tid; idx < 4096; idx += 256) {
        int tr = idx >> 6, ec = idx & 63;
        tile[tr][ec] = kb[(size_t)(t0 + tr) * EE + e0 + ec];
    }
    __syncthreads();
    for (int idx = tid; idx < 4096; idx += 256) {
        int d = idx >> 6, tl = idx & 63;
        kt[(size_t)(e0 + d) * LP + t0 + tl] = tile[tl][d];
    }
}

// bg[e] = S*bv[e] + (Wv . sumx)[e] - sum_{t<L} vb[t][e].  One wave per e.
__global__ __launch_bounds__(256) void bg_kernel(
    const int* __restrict__ meta, const float* __restrict__ Wv,
    const float* __restrict__ bv, const float* __restrict__ sumx,
    const float* __restrict__ vb, float* __restrict__ bg) {
    int L = meta[1];
    int gid  = blockIdx.x * 256 + threadIdx.x;
    int e    = gid >> 6;
    int lane = gid & 63;
    float p = 0.f;
    const float* wr = Wv + (size_t)e * EE;
    for (int j0 = 0; j0 < EE; j0 += 64) p += wr[j0 + lane] * sumx[j0 + lane];
    for (int t = lane; t < L; t += 64) p -= vb[(size_t)t * EE + e];
#pragma unroll
    for (int off = 32; off; off >>= 1) p += __shfl_xor(p, off);
    if (lane == 0) bg[e] = p + (float)SS * bv[e];
}

// attention: one wave per (segment-row, head). lane=t for scores, lane=d for PV.
__global__ __launch_bounds__(64) void attn_kernel(
    const int* __restrict__ meta, float* __restrict__ qb,
    const float* __restrict__ kt, const float* __restrict__ vb,
    const float* __restrict__ bg) {
    __shared__ float sc[8][64];
    int L = meta[1];
    int lane = threadIdx.x;
    int nt = (L + 63) >> 6;
    int total = L * HH;
    for (int it = blockIdx.x; it < total; it += gridDim.x) {
        int h  = it & (HH - 1);
        int sl = it >> 4;
        float qreg = qb[(size_t)sl * EE + h * DD + lane];
        const float* kth = kt + (size_t)(h * DD) * LP;
        float mmax = (L < SS) ? 0.f : -3.0e38f;
        for (int t0 = 0; t0 < nt; ++t0) {
            float s = 0.f;
            const float* kp = kth + t0 * 64 + lane;
#pragma unroll
            for (int d = 0; d < 64; ++d) {
                float qd = __shfl(qreg, d);
                s += qd * kp[(size_t)d * LP];
            }
            sc[t0][lane] = s;
            bool valid = (t0 * 64 + lane) < L;
            mmax = fmaxf(mmax, valid ? s : -3.0e38f);
        }
#pragma unroll
        for (int off = 32; off; off >>= 1) mmax = fmaxf(mmax, __shfl_xor(mmax, off));
        float Zl = 0.f;
        for (int t0 = 0; t0 < nt; ++t0) {
            bool valid = (t0 * 64 + lane) < L;
            float w = valid ? __expf(sc[t0][lane] - mmax) : 0.f;
            Zl += w;
            sc[t0][lane] = w;
        }
#pragma unroll
        for (int off = 32; off; off >>= 1) Zl += __shfl_xor(Zl, off);
        float Z = Zl + (float)(SS - L) * __expf(-mmax);
        __syncthreads();
        float acc = 0.f;
        for (int t0 = 0; t0 < nt; ++t0) {
            const float* vp = vb + (size_t)(t0 * 64) * EE + h * DD + lane;
#pragma unroll
            for (int tt = 0; tt < 64; ++tt) acc += sc[t0][tt] * vp[(size_t)tt * EE];
        }
        float o = (acc + __expf(-mmax) * bg[h * DD + lane]) / Z;
        __syncthreads();
        qb[(size_t)sl * EE + h * DD + lane] = o;
    }
}

// mwv[e] = sum over segment rows of wv (division by L folded into out_kernel)
__global__ void mean_kernel(const int* __restrict__ meta, const float* __restrict__ wv,
                            float* __restrict__ mwv) {
    int L = meta[1];
    int e = blockIdx.x * 256 + threadIdx.x;
    int tc = blockIdx.y;
    float a = 0.f;
    for (int t = tc; t < L; t += 16) a += wv[(size_t)t * EE + e];
    atomicAdd(&mwv[e], a);
}

// out[e] = (mwv . Wo[e,:]) / L + bo[e]; one wave per output element
__global__ __launch_bounds__(256) void out_kernel(
    const int* __restrict__ meta, const float* __restrict__ mwv,
    const float* __restrict__ Wo, const float* __restrict__ bo,
    float* __restrict__ out) {
    int L = meta[1];
    int gid  = blockIdx.x * 256 + threadIdx.x;
    int e    = gid >> 6;
    int lane = gid & 63;
    float a = 0.f;
    const float* wrow = Wo + (size_t)e * EE;
    for (int j0 = 0; j0 < EE; j0 += 64) a += mwv[j0 + lane] * wrow[j0 + lane];
#pragma unroll
    for (int off = 32; off; off >>= 1) a += __shfl_xor(a, off);
    if (lane == 0) out[e] = a / (float)L + bo[e];
}

extern "C" void kernel_launch(void* const* d_in, const int* in_sizes, int n_in,
                              void* d_out, int out_size, void* d_ws, size_t ws_size,
                              hipStream_t stream) {
    const float* x   = (const float*)d_in[0];
    const float* Wq  = (const float*)d_in[1];
    const float* bq  = (const float*)d_in[2];
    const float* Wk  = (const float*)d_in[3];
    const float* bk  = (const float*)d_in[4];
    const float* Wv  = (const float*)d_in[5];
    const float* bv  = (const float*)d_in[6];
    const float* Wo  = (const float*)d_in[7];
    const float* bo  = (const float*)d_in[8];
    const int*   seg = (const int*)d_in[9];
    const int*   pos = (const int*)d_in[10];
    float*       out = (float*)d_out;

    int*   meta = (int*)d_ws;
    float* fws  = (float*)d_ws;
    float* sumx = fws + 64;
    float* bg   = fws + 64 + EE;
    float* mwv  = fws + 64 + 2 * EE;

    size_t ktbytes = (size_t)EE * LP * sizeof(float);
    size_t avail   = (ws_size > 16384 + ktbytes) ? (ws_size - 16384 - ktbytes) : 0;
    int    caprows = (int)(avail / (3ull * EE * sizeof(float)));
    if (caprows > SS + 64) caprows = SS + 64;
    float* qb = (float*)((char*)d_ws + 16384);
    float* kb = qb + (size_t)caprows * EE;
    float* vb = kb + (size_t)caprows * EE;
    float* kt = vb + (size_t)caprows * EE;

    // zero sumx/bg/mwv (atomic accumulators)
    hipMemsetAsync(sumx, 0, 3 * EE * sizeof(float), stream);

    prep_kernel<<<dim3(4, 64), 256, 0, stream>>>(x, seg, pos, sumx, meta, caprows);
    proj_kernel<<<1024, 256, 0, stream>>>(x, Wq, bq, Wk, bk, Wv, bv, meta, qb, kb, vb);
    kt_kernel<<<dim3(8, 16), 256, 0, stream>>>(meta, kb, kt);
    bg_kernel<<<256, 256, 0, stream>>>(meta, Wv, bv, sumx, vb, bg);
    attn_kernel<<<1024, 64, 0, stream>>>(meta, qb, kt, vb, bg);
    mean_kernel<<<dim3(4, 16), 256, 0, stream>>>(meta, qb, mwv);
    out_kernel<<<256, 256, 0, stream>>>(meta, mwv, Wo, bo, out);
}